// Round 5
// baseline (2972.035 us; speedup 1.0000x reference)
//
#include <hip/hip_runtime.h>
#include <cstdint>
#include <cstddef>

#define LRELU(v) ((v) > 0.0f ? (v) : 0.2f * (v))

// ---------------------------------------------------------------------------
// 128x128 tile fp32 GEMM, C = leaky_relu(A[M,K] @ W[K,N] + bias[N])
// 256 threads, 8x8 micro-tile (2x 4-row / 2x 4-col halves).
// ---------------------------------------------------------------------------
__global__ __launch_bounds__(256, 2)
void sgemm_lrelu_128(const float* __restrict__ A, const float* __restrict__ W,
                     const float* __restrict__ bias, float* __restrict__ C,
                     int M, int N, int K)
{
    __shared__ float As[16][132];
    __shared__ float Bs[16][132];
    const int tid = threadIdx.x;
    const int tx = tid & 15, ty = tid >> 4;
    const int col0 = blockIdx.x * 128;
    const int row0 = blockIdx.y * 128;

    const int ar = tid >> 2;          // 0..63
    const int ac = (tid & 3) << 2;    // 0,4,8,12
    const int bk = tid >> 5;          // 0..7
    const int bn = (tid & 31) << 2;   // 0..124

    const float* Ap0 = A + (size_t)(row0 + ar) * K + ac;
    const float* Ap1 = Ap0 + (size_t)64 * K;
    const float* Wp0 = W + (size_t)bk * N + col0 + bn;
    const float* Wp1 = Wp0 + (size_t)8 * N;

    float acc[2][4][2][4];
#pragma unroll
    for (int rh = 0; rh < 2; ++rh)
#pragma unroll
        for (int i = 0; i < 4; ++i)
#pragma unroll
            for (int ch = 0; ch < 2; ++ch)
#pragma unroll
                for (int j = 0; j < 4; ++j) acc[rh][i][ch][j] = 0.0f;

    for (int k0 = 0; k0 < K; k0 += 16) {
        float4 a0 = *(const float4*)(Ap0 + k0);
        float4 a1 = *(const float4*)(Ap1 + k0);
        float4 b0 = *(const float4*)(Wp0 + (size_t)k0 * N);
        float4 b1 = *(const float4*)(Wp1 + (size_t)k0 * N);
        __syncthreads();
        As[ac + 0][ar] = a0.x; As[ac + 1][ar] = a0.y;
        As[ac + 2][ar] = a0.z; As[ac + 3][ar] = a0.w;
        As[ac + 0][ar + 64] = a1.x; As[ac + 1][ar + 64] = a1.y;
        As[ac + 2][ar + 64] = a1.z; As[ac + 3][ar + 64] = a1.w;
        *(float4*)&Bs[bk][bn]     = b0;
        *(float4*)&Bs[bk + 8][bn] = b1;
        __syncthreads();
#pragma unroll
        for (int k = 0; k < 16; ++k) {
            float4 af0 = *(const float4*)&As[k][ty * 4];
            float4 af1 = *(const float4*)&As[k][64 + ty * 4];
            float4 bf0 = *(const float4*)&Bs[k][tx * 4];
            float4 bf1 = *(const float4*)&Bs[k][64 + tx * 4];
            float av[2][4] = {{af0.x, af0.y, af0.z, af0.w},
                              {af1.x, af1.y, af1.z, af1.w}};
            float bv[2][4] = {{bf0.x, bf0.y, bf0.z, bf0.w},
                              {bf1.x, bf1.y, bf1.z, bf1.w}};
#pragma unroll
            for (int rh = 0; rh < 2; ++rh)
#pragma unroll
                for (int i = 0; i < 4; ++i)
#pragma unroll
                    for (int ch = 0; ch < 2; ++ch)
#pragma unroll
                        for (int j = 0; j < 4; ++j)
                            acc[rh][i][ch][j] += av[rh][i] * bv[ch][j];
        }
    }
#pragma unroll
    for (int rh = 0; rh < 2; ++rh)
#pragma unroll
        for (int i = 0; i < 4; ++i) {
            int row = row0 + rh * 64 + ty * 4 + i;
#pragma unroll
            for (int ch = 0; ch < 2; ++ch) {
                int col = col0 + ch * 64 + tx * 4;
                float4 bv = *(const float4*)(bias + col);
                float4 o;
                o.x = LRELU(acc[rh][i][ch][0] + bv.x);
                o.y = LRELU(acc[rh][i][ch][1] + bv.y);
                o.z = LRELU(acc[rh][i][ch][2] + bv.z);
                o.w = LRELU(acc[rh][i][ch][3] + bv.w);
                *(float4*)(C + (size_t)row * N + col) = o;
            }
        }
}

// ---------------------------------------------------------------------------
// 64x64 tile fp32 GEMM (for N in {128,256})
// ---------------------------------------------------------------------------
__global__ __launch_bounds__(256, 2)
void sgemm_lrelu_64(const float* __restrict__ A, const float* __restrict__ W,
                    const float* __restrict__ bias, float* __restrict__ C,
                    int M, int N, int K)
{
    __shared__ float As[16][68];
    __shared__ float Bs[16][68];
    const int tid = threadIdx.x;
    const int tx = tid & 15, ty = tid >> 4;
    const int col0 = blockIdx.x * 64;
    const int row0 = blockIdx.y * 64;

    const int ar = tid >> 2;          // 0..63
    const int ac = (tid & 3) << 2;    // 0,4,8,12
    const int bk = tid >> 4;          // 0..15
    const int bn = (tid & 15) << 2;   // 0..60

    const float* Ap = A + (size_t)(row0 + ar) * K + ac;
    const float* Wp = W + (size_t)bk * N + col0 + bn;

    float acc[4][4];
#pragma unroll
    for (int i = 0; i < 4; ++i)
#pragma unroll
        for (int j = 0; j < 4; ++j) acc[i][j] = 0.0f;

    for (int k0 = 0; k0 < K; k0 += 16) {
        float4 a0 = *(const float4*)(Ap + k0);
        float4 b0 = *(const float4*)(Wp + (size_t)k0 * N);
        __syncthreads();
        As[ac + 0][ar] = a0.x; As[ac + 1][ar] = a0.y;
        As[ac + 2][ar] = a0.z; As[ac + 3][ar] = a0.w;
        *(float4*)&Bs[bk][bn] = b0;
        __syncthreads();
#pragma unroll
        for (int k = 0; k < 16; ++k) {
            float4 af = *(const float4*)&As[k][ty * 4];
            float4 bf = *(const float4*)&Bs[k][tx * 4];
            float av[4] = {af.x, af.y, af.z, af.w};
            float bv[4] = {bf.x, bf.y, bf.z, bf.w};
#pragma unroll
            for (int i = 0; i < 4; ++i)
#pragma unroll
                for (int j = 0; j < 4; ++j) acc[i][j] += av[i] * bv[j];
        }
    }
#pragma unroll
    for (int i = 0; i < 4; ++i) {
        int row = row0 + ty * 4 + i;
        int col = col0 + tx * 4;
        float4 bv = *(const float4*)(bias + col);
        float4 o;
        o.x = LRELU(acc[i][0] + bv.x);
        o.y = LRELU(acc[i][1] + bv.y);
        o.z = LRELU(acc[i][2] + bv.z);
        o.w = LRELU(acc[i][3] + bv.w);
        *(float4*)(C + (size_t)row * N + col) = o;
    }
}

// ---------------------------------------------------------------------------
// codebook row squared-norms: grid 2048, block 64
// ---------------------------------------------------------------------------
__global__ void code_norms(const float* __restrict__ cb, float* __restrict__ cnorm)
{
    int j = blockIdx.x;
    int t = threadIdx.x;
    float a = cb[(size_t)j * 128 + t];
    float b = cb[(size_t)j * 128 + 64 + t];
    float s = a * a + b * b;
#pragma unroll
    for (int m = 1; m < 64; m <<= 1) s += __shfl_xor(s, m);
    if (t == 0) cnorm[j] = s;
}

// ---------------------------------------------------------------------------
// VQ argmin over 2048 codes; idx[r] stored as raw int in the first 4 bytes of
// row r of the (fp32) quantized output region — relay surviving scratch wipe.
// ---------------------------------------------------------------------------
__global__ __launch_bounds__(256, 2)
void vq_argmin(const float* __restrict__ flat, const float* __restrict__ cb,
               const float* __restrict__ cnorm, float* __restrict__ quant_out)
{
    __shared__ float Fs[128][68];   // [k][row] transposed
    __shared__ float Cs[16][132];   // [k][code] transposed
    __shared__ float Ns[128];
    const int tid = threadIdx.x;
    const int tx = tid & 15, ty = tid >> 4;
    const int row0 = blockIdx.x * 64;

    {   // stage f-tile (64 rows x 128 k), transposed
        int fr = tid >> 2;
        int fc = (tid & 3) << 2;
        const float* fp = flat + (size_t)(row0 + fr) * 128 + fc;
#pragma unroll
        for (int p = 0; p < 8; ++p) {
            float4 v = *(const float4*)(fp + p * 16);
            int k = fc + p * 16;
            Fs[k + 0][fr] = v.x; Fs[k + 1][fr] = v.y;
            Fs[k + 2][fr] = v.z; Fs[k + 3][fr] = v.w;
        }
    }

    float bestv[4];
    int   besti[4];
#pragma unroll
    for (int i = 0; i < 4; ++i) { bestv[i] = 3.402823466e+38f; besti[i] = 0; }

    for (int ct = 0; ct < 16; ++ct) {
        int c0 = ct * 128;
        __syncthreads();                    // protect Ns (and first-iter Fs)
        if (tid < 128) Ns[tid] = cnorm[c0 + tid];

        float acc[4][2][4];
#pragma unroll
        for (int i = 0; i < 4; ++i)
#pragma unroll
            for (int ch = 0; ch < 2; ++ch)
#pragma unroll
                for (int j = 0; j < 4; ++j) acc[i][ch][j] = 0.0f;

        for (int k0 = 0; k0 < 128; k0 += 16) {
            int cj = tid >> 1;              // 0..127
            int ck = (tid & 1) << 3;        // 0,8
            const float* cp = cb + (size_t)(c0 + cj) * 128 + k0 + ck;
            float4 v0 = *(const float4*)cp;
            float4 v1 = *(const float4*)(cp + 4);
            __syncthreads();
            Cs[ck + 0][cj] = v0.x; Cs[ck + 1][cj] = v0.y;
            Cs[ck + 2][cj] = v0.z; Cs[ck + 3][cj] = v0.w;
            Cs[ck + 4][cj] = v1.x; Cs[ck + 5][cj] = v1.y;
            Cs[ck + 6][cj] = v1.z; Cs[ck + 7][cj] = v1.w;
            __syncthreads();
#pragma unroll
            for (int k = 0; k < 16; ++k) {
                float4 af  = *(const float4*)&Fs[k0 + k][ty * 4];
                float4 cf0 = *(const float4*)&Cs[k][tx * 4];
                float4 cf1 = *(const float4*)&Cs[k][64 + tx * 4];
                float av[4] = {af.x, af.y, af.z, af.w};
                float cv[2][4] = {{cf0.x, cf0.y, cf0.z, cf0.w},
                                  {cf1.x, cf1.y, cf1.z, cf1.w}};
#pragma unroll
                for (int i = 0; i < 4; ++i)
#pragma unroll
                    for (int ch = 0; ch < 2; ++ch)
#pragma unroll
                        for (int j = 0; j < 4; ++j)
                            acc[i][ch][j] += av[i] * cv[ch][j];
            }
        }
        // per-row min over this code tile, then merge into running best
#pragma unroll
        for (int i = 0; i < 4; ++i) {
            float tv = 3.402823466e+38f;
            int   ti = 0;
#pragma unroll
            for (int ch = 0; ch < 2; ++ch)
#pragma unroll
                for (int j = 0; j < 4; ++j) {
                    int cc = ch * 64 + tx * 4 + j;
                    float s = Ns[cc] - 2.0f * acc[i][ch][j];
                    int ci = c0 + cc;
                    if (s < tv || (s == tv && ci < ti)) { tv = s; ti = ci; }
                }
#pragma unroll
            for (int m = 1; m < 16; m <<= 1) {
                float ov = __shfl_xor(tv, m);
                int   oi = __shfl_xor(ti, m);
                if (ov < tv || (ov == tv && oi < ti)) { tv = ov; ti = oi; }
            }
            if (tv < bestv[i] || (tv == bestv[i] && ti < besti[i])) {
                bestv[i] = tv; besti[i] = ti;
            }
        }
    }
    if (tx == 0) {
#pragma unroll
        for (int i = 0; i < 4; ++i) {
            int r = row0 + ty * 4 + i;
            *(int*)(quant_out + (size_t)r * 128) = besti[i];  // idx relay
        }
    }
}

// ---------------------------------------------------------------------------
// scratch gather: quant_s[r][:] = codebook[idx_slot(r)][:]  (one wave per row)
// ---------------------------------------------------------------------------
__global__ void vq_gather_scratch(const float* __restrict__ quant_out,
                                  const float* __restrict__ cb,
                                  float* __restrict__ quant_s)
{
    int w = (blockIdx.x * 256 + threadIdx.x) >> 6;   // row 0..65535
    int l = threadIdx.x & 63;
    int ix = *(const int*)(quant_out + (size_t)w * 128);
    float2 v = *(const float2*)(cb + (size_t)ix * 128 + 2 * l);
    *(float2*)(quant_s + (size_t)w * 128 + 2 * l) = v;
}

// ---------------------------------------------------------------------------
// final gather (LAST): overwrites quant row incl. its own idx slot — in-wave
// load-before-store makes the self-overlap safe.
// ---------------------------------------------------------------------------
__global__ void vq_gather_final(float* __restrict__ quant_out,
                                const float* __restrict__ cb)
{
    int w = (blockIdx.x * 256 + threadIdx.x) >> 6;   // row
    int l = threadIdx.x & 63;
    int ix = *(const int*)(quant_out + (size_t)w * 128);
    float2 v = *(const float2*)(cb + (size_t)ix * 128 + 2 * l);
    *(float2*)(quant_out + (size_t)w * 128 + 2 * l) = v;
}

// ---------------------------------------------------------------------------
// one-hot row writer (fp32): block r writes the full 2048-wide row.
// Wipes all disc-region scratch. Reads idx from quant region (disjoint).
// ---------------------------------------------------------------------------
__global__ void onehot_rows(const float* __restrict__ quant_out,
                            float* __restrict__ disc)
{
    int r = blockIdx.x;
    int t = threadIdx.x;
    int ix = *(const int*)(quant_out + (size_t)r * 128);
    int c = t * 8;
    float4 o0 = {0.f, 0.f, 0.f, 0.f}, o1 = {0.f, 0.f, 0.f, 0.f};
    if (ix >= c && ix < c + 8) {
        float* po = (ix < c + 4) ? &o0.x : &o1.x;
        po[ix & 3] = 1.0f;
    }
    float* base = disc + (size_t)r * 2048 + c;
    *(float4*)(base)     = o0;
    *(float4*)(base + 4) = o1;
}

// ---------------------------------------------------------------------------
extern "C" void kernel_launch(void* const* d_in, const int* in_sizes, int n_in,
                              void* d_out, int out_size, void* d_ws, size_t ws_size,
                              hipStream_t stream)
{
    const float* cond = (const float*)d_in[0];
    const float* cb   = (const float*)d_in[1];
    const float* We1 = (const float*)d_in[2];  const float* be1 = (const float*)d_in[3];
    const float* We2 = (const float*)d_in[4];  const float* be2 = (const float*)d_in[5];
    const float* We3 = (const float*)d_in[6];  const float* be3 = (const float*)d_in[7];
    const float* We4 = (const float*)d_in[8];  const float* be4 = (const float*)d_in[9];
    const float* Wd1 = (const float*)d_in[10]; const float* bd1 = (const float*)d_in[11];
    const float* Wd2 = (const float*)d_in[12]; const float* bd2 = (const float*)d_in[13];
    const float* Wd3 = (const float*)d_in[14]; const float* bd3 = (const float*)d_in[15];
    const float* Wd4 = (const float*)d_in[16]; const float* bd4 = (const float*)d_in[17];

    // fp32 output layout: recon | encoded | discrete | quantized
    float* out     = (float*)d_out;
    float* recon   = out;                            // 1,048,576
    float* encoded = out + 1048576;                  // 8,388,608
    float* disc    = out + 1048576 + 8388608;        // 134,217,728
    float* quant   = disc + 134217728;               // 8,388,608

    // fp32 scratch inside the disc region (134M floats; we use ~27M),
    // wiped by onehot_rows at the end. d_ws untouched.
    float* quant_s = disc;                           // 8,388,608
    float* bufA    = quant_s + 8388608;              // 8,388,608
    float* bufB    = bufA    + 8388608;              // 8,388,608
    float* x1      = bufB    + 8388608;              // 524,288
    float* y3      = x1      + 524288;               // 524,288
    float* cnorm   = y3      + 524288 + 4096;        // 2,048 (+pad for hygiene)

    dim3 blk(256);

    code_norms<<<2048, 64, 0, stream>>>(cb, cnorm);
    // --- encoder (fp32: argmin must match fp32 reference) ---
    sgemm_lrelu_64 <<<dim3(2, 64),  blk, 0, stream>>>(cond, We1, be1, x1,      4096, 128,  256);
    sgemm_lrelu_128<<<dim3(16, 32), blk, 0, stream>>>(x1,   We2, be2, bufA,    4096, 2048, 128);
    sgemm_lrelu_128<<<dim3(16, 32), blk, 0, stream>>>(bufA, We3, be3, bufB,    4096, 2048, 2048);
    sgemm_lrelu_128<<<dim3(16, 32), blk, 0, stream>>>(bufB, We4, be4, encoded, 4096, 2048, 2048);
    // --- VQ: idx ints into quantized-region row slots ---
    vq_argmin<<<1024, blk, 0, stream>>>(encoded, cb, cnorm, quant);
    vq_gather_scratch<<<16384, blk, 0, stream>>>(quant, cb, quant_s);
    // --- decoder (fp32) ---
    sgemm_lrelu_128<<<dim3(16, 32), blk, 0, stream>>>(quant_s, Wd1, bd1, bufA, 4096, 2048, 2048);
    sgemm_lrelu_128<<<dim3(16, 32), blk, 0, stream>>>(bufA,    Wd2, bd2, bufB, 4096, 2048, 2048);
    sgemm_lrelu_64 <<<dim3(2, 64),  blk, 0, stream>>>(bufB,    Wd3, bd3, y3,   4096, 128,  2048);
    // FINAL LAYER: K = 128 (y3 is [4096,128]) — was the 416-blowup bug.
    sgemm_lrelu_64 <<<dim3(4, 64),  blk, 0, stream>>>(y3, Wd4, bd4, recon,     4096, 256,  128);
    // --- one-hot rows (wipes disc scratch; reads idx from quant region) ---
    onehot_rows<<<65536, blk, 0, stream>>>(quant, disc);
    // --- final fp32 quantized (consumes idx slots in-place) ---
    vq_gather_final<<<16384, blk, 0, stream>>>(quant, cb);
}

// Round 6
// 2268.986 us; speedup vs baseline: 1.3099x; 1.3099x over previous
//
#include <hip/hip_runtime.h>
#include <cstdint>
#include <cstddef>

#define LRELU(v) ((v) > 0.0f ? (v) : 0.2f * (v))

typedef __attribute__((ext_vector_type(8))) short bf16x8;
typedef __attribute__((ext_vector_type(4))) float f32x4;

// round-to-nearest-even fp32 -> bf16 bit pack
__device__ __forceinline__ unsigned short f2bf(float x) {
    unsigned int u = __float_as_uint(x);
    u += 0x7FFFu + ((u >> 16) & 1u);
    return (unsigned short)(u >> 16);
}

// ---------------------------------------------------------------------------
// 128x128 tile fp32 GEMM, C = leaky_relu(A[M,K] @ W[K,N] + bias[N])  (encoder)
// ---------------------------------------------------------------------------
__global__ __launch_bounds__(256, 2)
void sgemm_lrelu_128(const float* __restrict__ A, const float* __restrict__ W,
                     const float* __restrict__ bias, float* __restrict__ C,
                     int M, int N, int K)
{
    __shared__ float As[16][132];
    __shared__ float Bs[16][132];
    const int tid = threadIdx.x;
    const int tx = tid & 15, ty = tid >> 4;
    const int col0 = blockIdx.x * 128;
    const int row0 = blockIdx.y * 128;

    const int ar = tid >> 2;          // 0..63
    const int ac = (tid & 3) << 2;    // 0,4,8,12
    const int bk = tid >> 5;          // 0..7
    const int bn = (tid & 31) << 2;   // 0..124

    const float* Ap0 = A + (size_t)(row0 + ar) * K + ac;
    const float* Ap1 = Ap0 + (size_t)64 * K;
    const float* Wp0 = W + (size_t)bk * N + col0 + bn;
    const float* Wp1 = Wp0 + (size_t)8 * N;

    float acc[2][4][2][4];
#pragma unroll
    for (int rh = 0; rh < 2; ++rh)
#pragma unroll
        for (int i = 0; i < 4; ++i)
#pragma unroll
            for (int ch = 0; ch < 2; ++ch)
#pragma unroll
                for (int j = 0; j < 4; ++j) acc[rh][i][ch][j] = 0.0f;

    for (int k0 = 0; k0 < K; k0 += 16) {
        float4 a0 = *(const float4*)(Ap0 + k0);
        float4 a1 = *(const float4*)(Ap1 + k0);
        float4 b0 = *(const float4*)(Wp0 + (size_t)k0 * N);
        float4 b1 = *(const float4*)(Wp1 + (size_t)k0 * N);
        __syncthreads();
        As[ac + 0][ar] = a0.x; As[ac + 1][ar] = a0.y;
        As[ac + 2][ar] = a0.z; As[ac + 3][ar] = a0.w;
        As[ac + 0][ar + 64] = a1.x; As[ac + 1][ar + 64] = a1.y;
        As[ac + 2][ar + 64] = a1.z; As[ac + 3][ar + 64] = a1.w;
        *(float4*)&Bs[bk][bn]     = b0;
        *(float4*)&Bs[bk + 8][bn] = b1;
        __syncthreads();
#pragma unroll
        for (int k = 0; k < 16; ++k) {
            float4 af0 = *(const float4*)&As[k][ty * 4];
            float4 af1 = *(const float4*)&As[k][64 + ty * 4];
            float4 bf0 = *(const float4*)&Bs[k][tx * 4];
            float4 bf1 = *(const float4*)&Bs[k][64 + tx * 4];
            float av[2][4] = {{af0.x, af0.y, af0.z, af0.w},
                              {af1.x, af1.y, af1.z, af1.w}};
            float bv[2][4] = {{bf0.x, bf0.y, bf0.z, bf0.w},
                              {bf1.x, bf1.y, bf1.z, bf1.w}};
#pragma unroll
            for (int rh = 0; rh < 2; ++rh)
#pragma unroll
                for (int i = 0; i < 4; ++i)
#pragma unroll
                    for (int ch = 0; ch < 2; ++ch)
#pragma unroll
                        for (int j = 0; j < 4; ++j)
                            acc[rh][i][ch][j] += av[rh][i] * bv[ch][j];
        }
    }
#pragma unroll
    for (int rh = 0; rh < 2; ++rh)
#pragma unroll
        for (int i = 0; i < 4; ++i) {
            int row = row0 + rh * 64 + ty * 4 + i;
#pragma unroll
            for (int ch = 0; ch < 2; ++ch) {
                int col = col0 + ch * 64 + tx * 4;
                float4 bv = *(const float4*)(bias + col);
                float4 o;
                o.x = LRELU(acc[rh][i][ch][0] + bv.x);
                o.y = LRELU(acc[rh][i][ch][1] + bv.y);
                o.z = LRELU(acc[rh][i][ch][2] + bv.z);
                o.w = LRELU(acc[rh][i][ch][3] + bv.w);
                *(float4*)(C + (size_t)row * N + col) = o;
            }
        }
}

// ---------------------------------------------------------------------------
// 64x64 tile fp32 GEMM (We1: N=128, K=256)
// ---------------------------------------------------------------------------
__global__ __launch_bounds__(256, 2)
void sgemm_lrelu_64(const float* __restrict__ A, const float* __restrict__ W,
                    const float* __restrict__ bias, float* __restrict__ C,
                    int M, int N, int K)
{
    __shared__ float As[16][68];
    __shared__ float Bs[16][68];
    const int tid = threadIdx.x;
    const int tx = tid & 15, ty = tid >> 4;
    const int col0 = blockIdx.x * 64;
    const int row0 = blockIdx.y * 64;

    const int ar = tid >> 2;          // 0..63
    const int ac = (tid & 3) << 2;    // 0,4,8,12
    const int bk = tid >> 4;          // 0..15
    const int bn = (tid & 15) << 2;   // 0..60

    const float* Ap = A + (size_t)(row0 + ar) * K + ac;
    const float* Wp = W + (size_t)bk * N + col0 + bn;

    float acc[4][4];
#pragma unroll
    for (int i = 0; i < 4; ++i)
#pragma unroll
        for (int j = 0; j < 4; ++j) acc[i][j] = 0.0f;

    for (int k0 = 0; k0 < K; k0 += 16) {
        float4 a0 = *(const float4*)(Ap + k0);
        float4 b0 = *(const float4*)(Wp + (size_t)k0 * N);
        __syncthreads();
        As[ac + 0][ar] = a0.x; As[ac + 1][ar] = a0.y;
        As[ac + 2][ar] = a0.z; As[ac + 3][ar] = a0.w;
        *(float4*)&Bs[bk][bn] = b0;
        __syncthreads();
#pragma unroll
        for (int k = 0; k < 16; ++k) {
            float4 af = *(const float4*)&As[k][ty * 4];
            float4 bf = *(const float4*)&Bs[k][tx * 4];
            float av[4] = {af.x, af.y, af.z, af.w};
            float bv[4] = {bf.x, bf.y, bf.z, bf.w};
#pragma unroll
            for (int i = 0; i < 4; ++i)
#pragma unroll
                for (int j = 0; j < 4; ++j) acc[i][j] += av[i] * bv[j];
        }
    }
#pragma unroll
    for (int i = 0; i < 4; ++i) {
        int row = row0 + ty * 4 + i;
        int col = col0 + tx * 4;
        float4 bv = *(const float4*)(bias + col);
        float4 o;
        o.x = LRELU(acc[i][0] + bv.x);
        o.y = LRELU(acc[i][1] + bv.y);
        o.z = LRELU(acc[i][2] + bv.z);
        o.w = LRELU(acc[i][3] + bv.w);
        *(float4*)(C + (size_t)row * N + col) = o;
    }
}

// ---------------------------------------------------------------------------
// bf16 MFMA GEMM (decoder): C = leaky_relu(A[M,K] @ Bt[N,K]^T + bias[N])
// A bf16 row-major [M][K]; Bt bf16 row-major [N][K] (pre-transposed weight).
// 256 thr = 4 waves (2x2), wave = 64x64 = 4x4 frags of 16x16x32, BK=64.
// LDS [128][72] bf16: stride 36 words -> frag reads & staged writes
// conflict-free per 16-lane phase.
// Fragment layouts (guide §3, m89-verified C/D):
//   A/B operand: lane l holds row/col (l&15), k = (l>>4)*8 + j (8 contiguous)
//   C/D:         col = l&15, row = (l>>4)*4 + reg
// OBF: 1 -> bf16 out (Cb), 0 -> fp32 out (Cf)
// ---------------------------------------------------------------------------
template <int OBF>
__global__ __launch_bounds__(256, 2)
void hgemm_lrelu(const unsigned short* __restrict__ A,
                 const unsigned short* __restrict__ Bt,
                 const float* __restrict__ bias, float* __restrict__ Cf,
                 unsigned short* __restrict__ Cb, int M, int N, int K)
{
    __shared__ unsigned short As[128][72];
    __shared__ unsigned short Bs[128][72];
    const int tid  = threadIdx.x;
    const int lane = tid & 63;
    const int wave = tid >> 6;
    const int wm = wave >> 1, wn = wave & 1;
    const int m0 = blockIdx.y * 128, n0 = blockIdx.x * 128;
    const int fr  = lane & 15;
    const int fko = (lane >> 4) * 8;

    f32x4 acc[4][4] = {};

    for (int k0 = 0; k0 < K; k0 += 64) {
        __syncthreads();
#pragma unroll
        for (int s = 0; s < 4; ++s) {
            int slot = s * 256 + tid;          // 0..1023
            int row = slot >> 3;
            int ck  = (slot & 7) * 8;
            *(bf16x8*)&As[row][ck] =
                *(const bf16x8*)(A + (size_t)(m0 + row) * K + k0 + ck);
            *(bf16x8*)&Bs[row][ck] =
                *(const bf16x8*)(Bt + (size_t)(n0 + row) * K + k0 + ck);
        }
        __syncthreads();
#pragma unroll
        for (int ks = 0; ks < 2; ++ks) {
            bf16x8 a[4], b[4];
#pragma unroll
            for (int m = 0; m < 4; ++m)
                a[m] = *(const bf16x8*)&As[wm * 64 + m * 16 + fr][ks * 32 + fko];
#pragma unroll
            for (int n = 0; n < 4; ++n)
                b[n] = *(const bf16x8*)&Bs[wn * 64 + n * 16 + fr][ks * 32 + fko];
#pragma unroll
            for (int m = 0; m < 4; ++m)
#pragma unroll
                for (int n = 0; n < 4; ++n)
                    acc[m][n] = __builtin_amdgcn_mfma_f32_16x16x32_bf16(
                        a[m], b[n], acc[m][n], 0, 0, 0);
        }
    }

    const int r0 = (lane >> 4) * 4;
#pragma unroll
    for (int n = 0; n < 4; ++n) {
        int col = n0 + wn * 64 + n * 16 + fr;
        float bv = bias[col];
#pragma unroll
        for (int m = 0; m < 4; ++m) {
            int rowb = m0 + wm * 64 + m * 16 + r0;
#pragma unroll
            for (int r = 0; r < 4; ++r) {
                float v = acc[m][n][r] + bv;
                v = LRELU(v);
                if constexpr (OBF)
                    Cb[(size_t)(rowb + r) * N + col] = f2bf(v);
                else
                    Cf[(size_t)(rowb + r) * N + col] = v;
            }
        }
    }
}

// ---------------------------------------------------------------------------
// weight transpose + bf16 cast: W fp32 [K][N] -> Wt bf16 [N][K]  (32x32 tiles)
// ---------------------------------------------------------------------------
__global__ void transpose_w_bf16(const float* __restrict__ W,
                                 unsigned short* __restrict__ Wt, int K, int N)
{
    __shared__ unsigned short T[32][36];
    int t = threadIdx.x;
    int n0 = blockIdx.x * 32, k0 = blockIdx.y * 32;
    {
        int r = t >> 3, cq = (t & 7) * 4;
        float4 v = *(const float4*)(W + (size_t)(k0 + r) * N + n0 + cq);
        T[cq + 0][r] = f2bf(v.x);
        T[cq + 1][r] = f2bf(v.y);
        T[cq + 2][r] = f2bf(v.z);
        T[cq + 3][r] = f2bf(v.w);
    }
    __syncthreads();
    {
        int nr = t >> 3, kq = (t & 7) * 4;
        ushort4 o;
        o.x = T[nr][kq + 0]; o.y = T[nr][kq + 1];
        o.z = T[nr][kq + 2]; o.w = T[nr][kq + 3];
        *(ushort4*)(Wt + (size_t)(n0 + nr) * K + k0 + kq) = o;
    }
}

// ---------------------------------------------------------------------------
// codebook row squared-norms: grid 2048, block 64
// ---------------------------------------------------------------------------
__global__ void code_norms(const float* __restrict__ cb, float* __restrict__ cnorm)
{
    int j = blockIdx.x;
    int t = threadIdx.x;
    float a = cb[(size_t)j * 128 + t];
    float b = cb[(size_t)j * 128 + 64 + t];
    float s = a * a + b * b;
#pragma unroll
    for (int m = 1; m < 64; m <<= 1) s += __shfl_xor(s, m);
    if (t == 0) cnorm[j] = s;
}

// ---------------------------------------------------------------------------
// VQ argmin over 2048 codes (fp32; must match fp32 reference ordering).
// idx[r] stored as raw int in first 4 bytes of row r of the fp32 quantized
// output region (relay surviving the scratch wipe).
// ---------------------------------------------------------------------------
__global__ __launch_bounds__(256, 2)
void vq_argmin(const float* __restrict__ flat, const float* __restrict__ cb,
               const float* __restrict__ cnorm, float* __restrict__ quant_out)
{
    __shared__ float Fs[128][68];   // [k][row] transposed
    __shared__ float Cs[16][132];   // [k][code] transposed
    __shared__ float Ns[128];
    const int tid = threadIdx.x;
    const int tx = tid & 15, ty = tid >> 4;
    const int row0 = blockIdx.x * 64;

    {   // stage f-tile (64 rows x 128 k), transposed
        int frr = tid >> 2;
        int fcc = (tid & 3) << 2;
        const float* fp = flat + (size_t)(row0 + frr) * 128 + fcc;
#pragma unroll
        for (int p = 0; p < 8; ++p) {
            float4 v = *(const float4*)(fp + p * 16);
            int k = fcc + p * 16;
            Fs[k + 0][frr] = v.x; Fs[k + 1][frr] = v.y;
            Fs[k + 2][frr] = v.z; Fs[k + 3][frr] = v.w;
        }
    }

    float bestv[4];
    int   besti[4];
#pragma unroll
    for (int i = 0; i < 4; ++i) { bestv[i] = 3.402823466e+38f; besti[i] = 0; }

    for (int ct = 0; ct < 16; ++ct) {
        int c0 = ct * 128;
        __syncthreads();                    // protect Ns (and first-iter Fs)
        if (tid < 128) Ns[tid] = cnorm[c0 + tid];

        float acc[4][2][4];
#pragma unroll
        for (int i = 0; i < 4; ++i)
#pragma unroll
            for (int ch = 0; ch < 2; ++ch)
#pragma unroll
                for (int j = 0; j < 4; ++j) acc[i][ch][j] = 0.0f;

        for (int k0 = 0; k0 < 128; k0 += 16) {
            int cj = tid >> 1;              // 0..127
            int ck = (tid & 1) << 3;        // 0,8
            const float* cp = cb + (size_t)(c0 + cj) * 128 + k0 + ck;
            float4 v0 = *(const float4*)cp;
            float4 v1 = *(const float4*)(cp + 4);
            __syncthreads();
            Cs[ck + 0][cj] = v0.x; Cs[ck + 1][cj] = v0.y;
            Cs[ck + 2][cj] = v0.z; Cs[ck + 3][cj] = v0.w;
            Cs[ck + 4][cj] = v1.x; Cs[ck + 5][cj] = v1.y;
            Cs[ck + 6][cj] = v1.z; Cs[ck + 7][cj] = v1.w;
            __syncthreads();
#pragma unroll
            for (int k = 0; k < 16; ++k) {
                float4 af  = *(const float4*)&Fs[k0 + k][ty * 4];
                float4 cf0 = *(const float4*)&Cs[k][tx * 4];
                float4 cf1 = *(const float4*)&Cs[k][64 + tx * 4];
                float av[4] = {af.x, af.y, af.z, af.w};
                float cv[2][4] = {{cf0.x, cf0.y, cf0.z, cf0.w},
                                  {cf1.x, cf1.y, cf1.z, cf1.w}};
#pragma unroll
                for (int i = 0; i < 4; ++i)
#pragma unroll
                    for (int ch = 0; ch < 2; ++ch)
#pragma unroll
                        for (int j = 0; j < 4; ++j)
                            acc[i][ch][j] += av[i] * cv[ch][j];
            }
        }
#pragma unroll
        for (int i = 0; i < 4; ++i) {
            float tv = 3.402823466e+38f;
            int   ti = 0;
#pragma unroll
            for (int ch = 0; ch < 2; ++ch)
#pragma unroll
                for (int j = 0; j < 4; ++j) {
                    int cc = ch * 64 + tx * 4 + j;
                    float s = Ns[cc] - 2.0f * acc[i][ch][j];
                    int ci = c0 + cc;
                    if (s < tv || (s == tv && ci < ti)) { tv = s; ti = ci; }
                }
#pragma unroll
            for (int m = 1; m < 16; m <<= 1) {
                float ov = __shfl_xor(tv, m);
                int   oi = __shfl_xor(ti, m);
                if (ov < tv || (ov == tv && oi < ti)) { tv = ov; ti = oi; }
            }
            if (tv < bestv[i] || (tv == bestv[i] && ti < besti[i])) {
                bestv[i] = tv; besti[i] = ti;
            }
        }
    }
    if (tx == 0) {
#pragma unroll
        for (int i = 0; i < 4; ++i) {
            int r = row0 + ty * 4 + i;
            *(int*)(quant_out + (size_t)r * 128) = besti[i];  // idx relay
        }
    }
}

// ---------------------------------------------------------------------------
// bf16 gather for decoder input: qb[r][:] = bf16(codebook[idx_slot(r)][:])
// ---------------------------------------------------------------------------
__global__ void vq_gather_bf16(const float* __restrict__ quant_out,
                               const float* __restrict__ cb,
                               unsigned short* __restrict__ qb)
{
    int w = (blockIdx.x * 256 + threadIdx.x) >> 6;   // row 0..65535
    int l = threadIdx.x & 63;
    int ix = *(const int*)(quant_out + (size_t)w * 128);
    float2 v = *(const float2*)(cb + (size_t)ix * 128 + 2 * l);
    unsigned int p = (unsigned int)f2bf(v.x) | ((unsigned int)f2bf(v.y) << 16);
    ((unsigned int*)qb)[(size_t)w * 64 + l] = p;
}

// ---------------------------------------------------------------------------
// final fp32 gather (LAST): overwrites quant row incl. its own idx slot —
// in-wave load-before-store makes the self-overlap safe.
// ---------------------------------------------------------------------------
__global__ void vq_gather_final(float* __restrict__ quant_out,
                                const float* __restrict__ cb)
{
    int w = (blockIdx.x * 256 + threadIdx.x) >> 6;   // row
    int l = threadIdx.x & 63;
    int ix = *(const int*)(quant_out + (size_t)w * 128);
    float2 v = *(const float2*)(cb + (size_t)ix * 128 + 2 * l);
    *(float2*)(quant_out + (size_t)w * 128 + 2 * l) = v;
}

// ---------------------------------------------------------------------------
// one-hot row writer (fp32): block r writes the full 2048-wide row.
// Wipes all disc-region scratch. Reads idx from quant region (disjoint).
// ---------------------------------------------------------------------------
__global__ void onehot_rows(const float* __restrict__ quant_out,
                            float* __restrict__ disc)
{
    int r = blockIdx.x;
    int t = threadIdx.x;
    int ix = *(const int*)(quant_out + (size_t)r * 128);
    int c = t * 8;
    float4 o0 = {0.f, 0.f, 0.f, 0.f}, o1 = {0.f, 0.f, 0.f, 0.f};
    if (ix >= c && ix < c + 8) {
        float* po = (ix < c + 4) ? &o0.x : &o1.x;
        po[ix & 3] = 1.0f;
    }
    float* base = disc + (size_t)r * 2048 + c;
    *(float4*)(base)     = o0;
    *(float4*)(base + 4) = o1;
}

// ---------------------------------------------------------------------------
extern "C" void kernel_launch(void* const* d_in, const int* in_sizes, int n_in,
                              void* d_out, int out_size, void* d_ws, size_t ws_size,
                              hipStream_t stream)
{
    const float* cond = (const float*)d_in[0];
    const float* cb   = (const float*)d_in[1];
    const float* We1 = (const float*)d_in[2];  const float* be1 = (const float*)d_in[3];
    const float* We2 = (const float*)d_in[4];  const float* be2 = (const float*)d_in[5];
    const float* We3 = (const float*)d_in[6];  const float* be3 = (const float*)d_in[7];
    const float* We4 = (const float*)d_in[8];  const float* be4 = (const float*)d_in[9];
    const float* Wd1 = (const float*)d_in[10]; const float* bd1 = (const float*)d_in[11];
    const float* Wd2 = (const float*)d_in[12]; const float* bd2 = (const float*)d_in[13];
    const float* Wd3 = (const float*)d_in[14]; const float* bd3 = (const float*)d_in[15];
    const float* Wd4 = (const float*)d_in[16]; const float* bd4 = (const float*)d_in[17];

    // fp32 output layout: recon | encoded | discrete | quantized
    float* out     = (float*)d_out;
    float* recon   = out;                            // 1,048,576
    float* encoded = out + 1048576;                  // 8,388,608
    float* disc    = out + 1048576 + 8388608;        // 134,217,728
    float* quant   = disc + 134217728;               // 8,388,608

    // Scratch inside the disc region (134M floats; ~34.5M used), wiped by
    // onehot_rows at the end. d_ws untouched.
    unsigned short* sb = (unsigned short*)disc;
    unsigned short* qb  = sb;                        //  8,388,608 us
    unsigned short* d1b = sb + 8388608;              //  8,388,608 us
    unsigned short* d2b = sb + 16777216;             //  8,388,608 us
    unsigned short* y3b = sb + 25165824;             //    524,288 us
    unsigned short* w1t = sb + 25690112;             //  4,194,304 us
    unsigned short* w2t = sb + 29884416;             //  4,194,304 us
    unsigned short* w3t = sb + 34078720;             //    262,144 us
    unsigned short* w4t = sb + 34340864;             //     32,768 us
    float* bufA  = disc + 17186816;                  //  8,388,608 f
    float* bufB  = bufA + 8388608;                   //  8,388,608 f
    float* x1    = bufB + 8388608;                   //    524,288 f
    float* cnorm = x1 + 524288;                      //      2,048 f

    dim3 blk(256);

    code_norms<<<2048, 64, 0, stream>>>(cb, cnorm);
    // weight transposes for decoder MFMA (independent of everything else)
    transpose_w_bf16<<<dim3(64, 64), blk, 0, stream>>>(Wd1, w1t, 2048, 2048);
    transpose_w_bf16<<<dim3(64, 64), blk, 0, stream>>>(Wd2, w2t, 2048, 2048);
    transpose_w_bf16<<<dim3(4,  64), blk, 0, stream>>>(Wd3, w3t, 2048, 128);
    transpose_w_bf16<<<dim3(8,   4), blk, 0, stream>>>(Wd4, w4t, 128,  256);

    // --- encoder (fp32: argmin must match fp32 reference) ---
    sgemm_lrelu_64 <<<dim3(2, 64),  blk, 0, stream>>>(cond, We1, be1, x1,      4096, 128,  256);
    sgemm_lrelu_128<<<dim3(16, 32), blk, 0, stream>>>(x1,   We2, be2, bufA,    4096, 2048, 128);
    sgemm_lrelu_128<<<dim3(16, 32), blk, 0, stream>>>(bufA, We3, be3, bufB,    4096, 2048, 2048);
    sgemm_lrelu_128<<<dim3(16, 32), blk, 0, stream>>>(bufB, We4, be4, encoded, 4096, 2048, 2048);

    // --- VQ: idx ints into quantized-region row slots; bf16 decoder input ---
    vq_argmin<<<1024, blk, 0, stream>>>(encoded, cb, cnorm, quant);
    vq_gather_bf16<<<16384, blk, 0, stream>>>(quant, cb, qb);

    // --- decoder (bf16 MFMA, fp32 accumulate) ---
    hgemm_lrelu<1><<<dim3(16, 32), blk, 0, stream>>>(qb,  w1t, bd1, nullptr, d1b, 4096, 2048, 2048);
    hgemm_lrelu<1><<<dim3(16, 32), blk, 0, stream>>>(d1b, w2t, bd2, nullptr, d2b, 4096, 2048, 2048);
    hgemm_lrelu<1><<<dim3(1,  32), blk, 0, stream>>>(d2b, w3t, bd3, nullptr, y3b, 4096, 128,  2048);
    hgemm_lrelu<0><<<dim3(2,  32), blk, 0, stream>>>(y3b, w4t, bd4, recon, nullptr, 4096, 256, 128);

    // --- one-hot rows (wipes disc scratch; reads idx from quant region) ---
    onehot_rows<<<65536, blk, 0, stream>>>(quant, disc);
    // --- final fp32 quantized (consumes idx slots in-place) ---
    vq_gather_final<<<16384, blk, 0, stream>>>(quant, cb);
}

// Round 9
// 2189.834 us; speedup vs baseline: 1.3572x; 1.0361x over previous
//
#include <hip/hip_runtime.h>
#include <cstdint>
#include <cstddef>

#define LRELU(v) ((v) > 0.0f ? (v) : 0.2f * (v))

typedef __attribute__((ext_vector_type(8))) short bf16x8;
typedef __attribute__((ext_vector_type(4))) float f32x4;

// round-to-nearest-even fp32 -> bf16 bit pack
__device__ __forceinline__ unsigned short f2bf(float x) {
    unsigned int u = __float_as_uint(x);
    u += 0x7FFFu + ((u >> 16) & 1u);
    return (unsigned short)(u >> 16);
}

// ---------------------------------------------------------------------------
// 128x128 tile fp32 GEMM, C = leaky_relu(A[M,K] @ W[K,N] + bias[N])  (encoder)
// BK=32 (half the barriers of BK=16), 3 blocks/CU. K-accumulation order is
// identical to the BK=16 version -> bitwise-identical outputs.
// ---------------------------------------------------------------------------
__global__ __launch_bounds__(256, 3)
void sgemm_lrelu_128(const float* __restrict__ A, const float* __restrict__ W,
                     const float* __restrict__ bias, float* __restrict__ C,
                     int M, int N, int K)
{
    __shared__ float As[32][132];
    __shared__ float Bs[32][132];
    const int tid = threadIdx.x;
    const int tx = tid & 15, ty = tid >> 4;
    const int col0 = blockIdx.x * 128;
    const int row0 = blockIdx.y * 128;

    const int ar = tid >> 2;          // 0..63
    const int ac = (tid & 3) << 2;    // 0,4,8,12
    const int bk = tid >> 5;          // 0..7
    const int bn = (tid & 31) << 2;   // 0..124

    const float* Ap0 = A + (size_t)(row0 + ar) * K + ac;
    const float* Ap1 = Ap0 + (size_t)64 * K;
    const float* Wp0 = W + (size_t)bk * N + col0 + bn;

    float acc[2][4][2][4];
#pragma unroll
    for (int rh = 0; rh < 2; ++rh)
#pragma unroll
        for (int i = 0; i < 4; ++i)
#pragma unroll
            for (int ch = 0; ch < 2; ++ch)
#pragma unroll
                for (int j = 0; j < 4; ++j) acc[rh][i][ch][j] = 0.0f;

    for (int k0 = 0; k0 < K; k0 += 32) {
        float4 a00 = *(const float4*)(Ap0 + k0);
        float4 a01 = *(const float4*)(Ap0 + k0 + 16);
        float4 a10 = *(const float4*)(Ap1 + k0);
        float4 a11 = *(const float4*)(Ap1 + k0 + 16);
        float4 b0 = *(const float4*)(Wp0 + (size_t)(k0     ) * N);
        float4 b1 = *(const float4*)(Wp0 + (size_t)(k0 +  8) * N);
        float4 b2 = *(const float4*)(Wp0 + (size_t)(k0 + 16) * N);
        float4 b3 = *(const float4*)(Wp0 + (size_t)(k0 + 24) * N);
        __syncthreads();
        As[ac + 0][ar] = a00.x; As[ac + 1][ar] = a00.y;
        As[ac + 2][ar] = a00.z; As[ac + 3][ar] = a00.w;
        As[ac + 16][ar] = a01.x; As[ac + 17][ar] = a01.y;
        As[ac + 18][ar] = a01.z; As[ac + 19][ar] = a01.w;
        As[ac + 0][ar + 64] = a10.x; As[ac + 1][ar + 64] = a10.y;
        As[ac + 2][ar + 64] = a10.z; As[ac + 3][ar + 64] = a10.w;
        As[ac + 16][ar + 64] = a11.x; As[ac + 17][ar + 64] = a11.y;
        As[ac + 18][ar + 64] = a11.z; As[ac + 19][ar + 64] = a11.w;
        *(float4*)&Bs[bk     ][bn] = b0;
        *(float4*)&Bs[bk +  8][bn] = b1;
        *(float4*)&Bs[bk + 16][bn] = b2;
        *(float4*)&Bs[bk + 24][bn] = b3;
        __syncthreads();
#pragma unroll
        for (int k = 0; k < 32; ++k) {
            float4 af0 = *(const float4*)&As[k][ty * 4];
            float4 af1 = *(const float4*)&As[k][64 + ty * 4];
            float4 bf0 = *(const float4*)&Bs[k][tx * 4];
            float4 bf1 = *(const float4*)&Bs[k][64 + tx * 4];
            float av[2][4] = {{af0.x, af0.y, af0.z, af0.w},
                              {af1.x, af1.y, af1.z, af1.w}};
            float bv[2][4] = {{bf0.x, bf0.y, bf0.z, bf0.w},
                              {bf1.x, bf1.y, bf1.z, bf1.w}};
#pragma unroll
            for (int rh = 0; rh < 2; ++rh)
#pragma unroll
                for (int i = 0; i < 4; ++i)
#pragma unroll
                    for (int ch = 0; ch < 2; ++ch)
#pragma unroll
                        for (int j = 0; j < 4; ++j)
                            acc[rh][i][ch][j] += av[rh][i] * bv[ch][j];
        }
    }
#pragma unroll
    for (int rh = 0; rh < 2; ++rh)
#pragma unroll
        for (int i = 0; i < 4; ++i) {
            int row = row0 + rh * 64 + ty * 4 + i;
#pragma unroll
            for (int ch = 0; ch < 2; ++ch) {
                int col = col0 + ch * 64 + tx * 4;
                float4 bv = *(const float4*)(bias + col);
                float4 o;
                o.x = LRELU(acc[rh][i][ch][0] + bv.x);
                o.y = LRELU(acc[rh][i][ch][1] + bv.y);
                o.z = LRELU(acc[rh][i][ch][2] + bv.z);
                o.w = LRELU(acc[rh][i][ch][3] + bv.w);
                *(float4*)(C + (size_t)row * N + col) = o;
            }
        }
}

// ---------------------------------------------------------------------------
// 64x64 tile fp32 GEMM (We1: N=128, K=256)
// ---------------------------------------------------------------------------
__global__ __launch_bounds__(256, 2)
void sgemm_lrelu_64(const float* __restrict__ A, const float* __restrict__ W,
                    const float* __restrict__ bias, float* __restrict__ C,
                    int M, int N, int K)
{
    __shared__ float As[16][68];
    __shared__ float Bs[16][68];
    const int tid = threadIdx.x;
    const int tx = tid & 15, ty = tid >> 4;
    const int col0 = blockIdx.x * 64;
    const int row0 = blockIdx.y * 64;

    const int ar = tid >> 2;          // 0..63
    const int ac = (tid & 3) << 2;    // 0,4,8,12
    const int bk = tid >> 4;          // 0..15
    const int bn = (tid & 15) << 2;   // 0..60

    const float* Ap = A + (size_t)(row0 + ar) * K + ac;
    const float* Wp = W + (size_t)bk * N + col0 + bn;

    float acc[4][4];
#pragma unroll
    for (int i = 0; i < 4; ++i)
#pragma unroll
        for (int j = 0; j < 4; ++j) acc[i][j] = 0.0f;

    for (int k0 = 0; k0 < K; k0 += 16) {
        float4 a0 = *(const float4*)(Ap + k0);
        float4 b0 = *(const float4*)(Wp + (size_t)k0 * N);
        __syncthreads();
        As[ac + 0][ar] = a0.x; As[ac + 1][ar] = a0.y;
        As[ac + 2][ar] = a0.z; As[ac + 3][ar] = a0.w;
        *(float4*)&Bs[bk][bn] = b0;
        __syncthreads();
#pragma unroll
        for (int k = 0; k < 16; ++k) {
            float4 af = *(const float4*)&As[k][ty * 4];
            float4 bf = *(const float4*)&Bs[k][tx * 4];
            float av[4] = {af.x, af.y, af.z, af.w};
            float bv[4] = {bf.x, bf.y, bf.z, bf.w};
#pragma unroll
            for (int i = 0; i < 4; ++i)
#pragma unroll
                for (int j = 0; j < 4; ++j) acc[i][j] += av[i] * bv[j];
        }
    }
#pragma unroll
    for (int i = 0; i < 4; ++i) {
        int row = row0 + ty * 4 + i;
        int col = col0 + tx * 4;
        float4 bv = *(const float4*)(bias + col);
        float4 o;
        o.x = LRELU(acc[i][0] + bv.x);
        o.y = LRELU(acc[i][1] + bv.y);
        o.z = LRELU(acc[i][2] + bv.z);
        o.w = LRELU(acc[i][3] + bv.w);
        *(float4*)(C + (size_t)row * N + col) = o;
    }
}

// ---------------------------------------------------------------------------
// bf16 MFMA GEMM (decoder): C = leaky_relu(A[M,K] @ Bt[N,K]^T + bias[N])
// 4 waves (2x2), wave = 64x64 of 16x16x32 frags, BK=64, 3 blocks/CU.
// ---------------------------------------------------------------------------
template <int OBF>
__global__ __launch_bounds__(256, 3)
void hgemm_lrelu(const unsigned short* __restrict__ A,
                 const unsigned short* __restrict__ Bt,
                 const float* __restrict__ bias, float* __restrict__ Cf,
                 unsigned short* __restrict__ Cb, int M, int N, int K)
{
    __shared__ unsigned short As[128][72];
    __shared__ unsigned short Bs[128][72];
    const int tid  = threadIdx.x;
    const int lane = tid & 63;
    const int wave = tid >> 6;
    const int wm = wave >> 1, wn = wave & 1;
    const int m0 = blockIdx.y * 128, n0 = blockIdx.x * 128;
    const int fr  = lane & 15;
    const int fko = (lane >> 4) * 8;

    f32x4 acc[4][4] = {};

    for (int k0 = 0; k0 < K; k0 += 64) {
        __syncthreads();
#pragma unroll
        for (int s = 0; s < 4; ++s) {
            int slot = s * 256 + tid;          // 0..1023
            int row = slot >> 3;
            int ck  = (slot & 7) * 8;
            *(bf16x8*)&As[row][ck] =
                *(const bf16x8*)(A + (size_t)(m0 + row) * K + k0 + ck);
            *(bf16x8*)&Bs[row][ck] =
                *(const bf16x8*)(Bt + (size_t)(n0 + row) * K + k0 + ck);
        }
        __syncthreads();
#pragma unroll
        for (int ks = 0; ks < 2; ++ks) {
            bf16x8 a[4], b[4];
#pragma unroll
            for (int m = 0; m < 4; ++m)
                a[m] = *(const bf16x8*)&As[wm * 64 + m * 16 + fr][ks * 32 + fko];
#pragma unroll
            for (int n = 0; n < 4; ++n)
                b[n] = *(const bf16x8*)&Bs[wn * 64 + n * 16 + fr][ks * 32 + fko];
#pragma unroll
            for (int m = 0; m < 4; ++m)
#pragma unroll
                for (int n = 0; n < 4; ++n)
                    acc[m][n] = __builtin_amdgcn_mfma_f32_16x16x32_bf16(
                        a[m], b[n], acc[m][n], 0, 0, 0);
        }
    }

    const int r0 = (lane >> 4) * 4;
#pragma unroll
    for (int n = 0; n < 4; ++n) {
        int col = n0 + wn * 64 + n * 16 + fr;
        float bv = bias[col];
#pragma unroll
        for (int m = 0; m < 4; ++m) {
            int rowb = m0 + wm * 64 + m * 16 + r0;
#pragma unroll
            for (int r = 0; r < 4; ++r) {
                float v = acc[m][n][r] + bv;
                v = LRELU(v);
                if constexpr (OBF)
                    Cb[(size_t)(rowb + r) * N + col] = f2bf(v);
                else
                    Cf[(size_t)(rowb + r) * N + col] = v;
            }
        }
    }
}

// ---------------------------------------------------------------------------
// weight transpose + bf16 cast: W fp32 [K][N] -> Wt bf16 [N][K]  (32x32 tiles)
// ---------------------------------------------------------------------------
__global__ void transpose_w_bf16(const float* __restrict__ W,
                                 unsigned short* __restrict__ Wt, int K, int N)
{
    __shared__ unsigned short T[32][36];
    int t = threadIdx.x;
    int n0 = blockIdx.x * 32, k0 = blockIdx.y * 32;
    {
        int r = t >> 3, cq = (t & 7) * 4;
        float4 v = *(const float4*)(W + (size_t)(k0 + r) * N + n0 + cq);
        T[cq + 0][r] = f2bf(v.x);
        T[cq + 1][r] = f2bf(v.y);
        T[cq + 2][r] = f2bf(v.z);
        T[cq + 3][r] = f2bf(v.w);
    }
    __syncthreads();
    {
        int nr = t >> 3, kq = (t & 7) * 4;
        ushort4 o;
        o.x = T[nr][kq + 0]; o.y = T[nr][kq + 1];
        o.z = T[nr][kq + 2]; o.w = T[nr][kq + 3];
        *(ushort4*)(Wt + (size_t)(n0 + nr) * K + k0 + kq) = o;
    }
}

// ---------------------------------------------------------------------------
// codebook row squared-norms: grid 2048, block 64
// ---------------------------------------------------------------------------
__global__ void code_norms(const float* __restrict__ cb, float* __restrict__ cnorm)
{
    int j = blockIdx.x;
    int t = threadIdx.x;
    float a = cb[(size_t)j * 128 + t];
    float b = cb[(size_t)j * 128 + 64 + t];
    float s = a * a + b * b;
#pragma unroll
    for (int m = 1; m < 64; m <<= 1) s += __shfl_xor(s, m);
    if (t == 0) cnorm[j] = s;
}

// ---------------------------------------------------------------------------
// VQ argmin over 2048 codes (fp32, same accumulation order as before ->
// bitwise-identical decisions). BK=32 staging, 3 blocks/CU (52.2KB LDS).
// idx[r] stored in first 4 bytes of row r of the fp32 quantized output.
// ---------------------------------------------------------------------------
__global__ __launch_bounds__(256, 3)
void vq_argmin(const float* __restrict__ flat, const float* __restrict__ cb,
               const float* __restrict__ cnorm, float* __restrict__ quant_out)
{
    __shared__ float Fs[128][68];   // [k][row] transposed
    __shared__ float Cs[32][132];   // [k][code] transposed
    __shared__ float Ns[128];
    const int tid = threadIdx.x;
    const int tx = tid & 15, ty = tid >> 4;
    const int row0 = blockIdx.x * 64;

    {   // stage f-tile (64 rows x 128 k), transposed
        int frr = tid >> 2;
        int fcc = (tid & 3) << 2;
        const float* fp = flat + (size_t)(row0 + frr) * 128 + fcc;
#pragma unroll
        for (int p = 0; p < 8; ++p) {
            float4 v = *(const float4*)(fp + p * 16);
            int k = fcc + p * 16;
            Fs[k + 0][frr] = v.x; Fs[k + 1][frr] = v.y;
            Fs[k + 2][frr] = v.z; Fs[k + 3][frr] = v.w;
        }
    }

    float bestv[4];
    int   besti[4];
#pragma unroll
    for (int i = 0; i < 4; ++i) { bestv[i] = 3.402823466e+38f; besti[i] = 0; }

    for (int ct = 0; ct < 16; ++ct) {
        int c0 = ct * 128;
        __syncthreads();                    // prev epilogue done (Ns reuse)
        if (tid < 128) Ns[tid] = cnorm[c0 + tid];

        float acc[4][2][4];
#pragma unroll
        for (int i = 0; i < 4; ++i)
#pragma unroll
            for (int ch = 0; ch < 2; ++ch)
#pragma unroll
                for (int j = 0; j < 4; ++j) acc[i][ch][j] = 0.0f;

        for (int k0 = 0; k0 < 128; k0 += 32) {
            int cj = tid >> 1;              // 0..127
            int ck = (tid & 1) << 4;        // 0,16
            const float* cp = cb + (size_t)(c0 + cj) * 128 + k0 + ck;
            float4 v0 = *(const float4*)(cp);
            float4 v1 = *(const float4*)(cp + 4);
            float4 v2 = *(const float4*)(cp + 8);
            float4 v3 = *(const float4*)(cp + 12);
            __syncthreads();
            Cs[ck +  0][cj] = v0.x; Cs[ck +  1][cj] = v0.y;
            Cs[ck +  2][cj] = v0.z; Cs[ck +  3][cj] = v0.w;
            Cs[ck +  4][cj] = v1.x; Cs[ck +  5][cj] = v1.y;
            Cs[ck +  6][cj] = v1.z; Cs[ck +  7][cj] = v1.w;
            Cs[ck +  8][cj] = v2.x; Cs[ck +  9][cj] = v2.y;
            Cs[ck + 10][cj] = v2.z; Cs[ck + 11][cj] = v2.w;
            Cs[ck + 12][cj] = v3.x; Cs[ck + 13][cj] = v3.y;
            Cs[ck + 14][cj] = v3.z; Cs[ck + 15][cj] = v3.w;
            __syncthreads();
#pragma unroll
            for (int k = 0; k < 32; ++k) {
                float4 af  = *(const float4*)&Fs[k0 + k][ty * 4];
                float4 cf0 = *(const float4*)&Cs[k][tx * 4];
                float4 cf1 = *(const float4*)&Cs[k][64 + tx * 4];
                float av[4] = {af.x, af.y, af.z, af.w};
                float cv[2][4] = {{cf0.x, cf0.y, cf0.z, cf0.w},
                                  {cf1.x, cf1.y, cf1.z, cf1.w}};
#pragma unroll
                for (int i = 0; i < 4; ++i)
#pragma unroll
                    for (int ch = 0; ch < 2; ++ch)
#pragma unroll
                        for (int j = 0; j < 4; ++j)
                            acc[i][ch][j] += av[i] * cv[ch][j];
            }
        }
#pragma unroll
        for (int i = 0; i < 4; ++i) {
            float tv = 3.402823466e+38f;
            int   ti = 0;
#pragma unroll
            for (int ch = 0; ch < 2; ++ch)
#pragma unroll
                for (int j = 0; j < 4; ++j) {
                    int cc = ch * 64 + tx * 4 + j;
                    float s = Ns[cc] - 2.0f * acc[i][ch][j];
                    int ci = c0 + cc;
                    if (s < tv || (s == tv && ci < ti)) { tv = s; ti = ci; }
                }
#pragma unroll
            for (int m = 1; m < 16; m <<= 1) {
                float ov = __shfl_xor(tv, m);
                int   oi = __shfl_xor(ti, m);
                if (ov < tv || (ov == tv && oi < ti)) { tv = ov; ti = oi; }
            }
            if (tv < bestv[i] || (tv == bestv[i] && ti < besti[i])) {
                bestv[i] = tv; besti[i] = ti;
            }
        }
    }
    if (tx == 0) {
#pragma unroll
        for (int i = 0; i < 4; ++i) {
            int r = row0 + ty * 4 + i;
            *(int*)(quant_out + (size_t)r * 128) = besti[i];  // idx relay
        }
    }
}

// ---------------------------------------------------------------------------
// bf16 gather for decoder input: qb[r][:] = bf16(codebook[idx_slot(r)][:])
// ---------------------------------------------------------------------------
__global__ void vq_gather_bf16(const float* __restrict__ quant_out,
                               const float* __restrict__ cb,
                               unsigned short* __restrict__ qb)
{
    int w = (blockIdx.x * 256 + threadIdx.x) >> 6;   // row 0..65535
    int l = threadIdx.x & 63;
    int ix = *(const int*)(quant_out + (size_t)w * 128);
    float2 v = *(const float2*)(cb + (size_t)ix * 128 + 2 * l);
    unsigned int p = (unsigned int)f2bf(v.x) | ((unsigned int)f2bf(v.y) << 16);
    ((unsigned int*)qb)[(size_t)w * 64 + l] = p;
}

// ---------------------------------------------------------------------------
// final fp32 gather (LAST): overwrites quant row incl. its own idx slot —
// in-wave load-before-store makes the self-overlap safe.
// ---------------------------------------------------------------------------
__global__ void vq_gather_final(float* __restrict__ quant_out,
                                const float* __restrict__ cb)
{
    int w = (blockIdx.x * 256 + threadIdx.x) >> 6;   // row
    int l = threadIdx.x & 63;
    int ix = *(const int*)(quant_out + (size_t)w * 128);
    float2 v = *(const float2*)(cb + (size_t)ix * 128 + 2 * l);
    *(float2*)(quant_out + (size_t)w * 128 + 2 * l) = v;
}

// ---------------------------------------------------------------------------
// one-hot row writer (fp32): block r writes the full 2048-wide row.
// Wipes all disc-region scratch. Reads idx from quant region (disjoint).
// ---------------------------------------------------------------------------
__global__ void onehot_rows(const float* __restrict__ quant_out,
                            float* __restrict__ disc)
{
    int r = blockIdx.x;
    int t = threadIdx.x;
    int ix = *(const int*)(quant_out + (size_t)r * 128);
    int c = t * 8;
    float4 o0 = {0.f, 0.f, 0.f, 0.f}, o1 = {0.f, 0.f, 0.f, 0.f};
    if (ix >= c && ix < c + 8) {
        float* po = (ix < c + 4) ? &o0.x : &o1.x;
        po[ix & 3] = 1.0f;
    }
    float* base = disc + (size_t)r * 2048 + c;
    *(float4*)(base)     = o0;
    *(float4*)(base + 4) = o1;
}

// ---------------------------------------------------------------------------
extern "C" void kernel_launch(void* const* d_in, const int* in_sizes, int n_in,
                              void* d_out, int out_size, void* d_ws, size_t ws_size,
                              hipStream_t stream)
{
    const float* cond = (const float*)d_in[0];
    const float* cb   = (const float*)d_in[1];
    const float* We1 = (const float*)d_in[2];  const float* be1 = (const float*)d_in[3];
    const float* We2 = (const float*)d_in[4];  const float* be2 = (const float*)d_in[5];
    const float* We3 = (const float*)d_in[6];  const float* be3 = (const float*)d_in[7];
    const float* We4 = (const float*)d_in[8];  const float* be4 = (const float*)d_in[9];
    const float* Wd1 = (const float*)d_in[10]; const float* bd1 = (const float*)d_in[11];
    const float* Wd2 = (const float*)d_in[12]; const float* bd2 = (const float*)d_in[13];
    const float* Wd3 = (const float*)d_in[14]; const float* bd3 = (const float*)d_in[15];
    const float* Wd4 = (const float*)d_in[16]; const float* bd4 = (const float*)d_in[17];

    // fp32 output layout: recon | encoded | discrete | quantized
    float* out     = (float*)d_out;
    float* recon   = out;                            // 1,048,576
    float* encoded = out + 1048576;                  // 8,388,608
    float* disc    = out + 1048576 + 8388608;        // 134,217,728
    float* quant   = disc + 134217728;               // 8,388,608

    // Scratch inside the disc region (134M floats; ~34.5M used), wiped by
    // onehot_rows at the end. d_ws untouched.
    unsigned short* sb = (unsigned short*)disc;
    unsigned short* qb  = sb;                        //  8,388,608 us
    unsigned short* d1b = sb + 8388608;              //  8,388,608 us
    unsigned short* d2b = sb + 16777216;             //  8,388,608 us
    unsigned short* y3b = sb + 25165824;             //    524,288 us
    unsigned short* w1t = sb + 25690112;             //  4,194,304 us
    unsigned short* w2t = sb + 29884416;             //  4,194,304 us
    unsigned short* w3t = sb + 34078720;             //    262,144 us
    unsigned short* w4t = sb + 34340864;             //     32,768 us
    float* bufA  = disc + 17186816;                  //  8,388,608 f
    float* bufB  = bufA + 8388608;                   //  8,388,608 f
    float* x1    = bufB + 8388608;                   //    524,288 f
    float* cnorm = x1 + 524288;                      //      2,048 f

    dim3 blk(256);

    code_norms<<<2048, 64, 0, stream>>>(cb, cnorm);
    // weight transposes for decoder MFMA (independent of everything else)
    transpose_w_bf16<<<dim3(64, 64), blk, 0, stream>>>(Wd1, w1t, 2048, 2048);
    transpose_w_bf16<<<dim3(64, 64), blk, 0, stream>>>(Wd2, w2t, 2048, 2048);
    transpose_w_bf16<<<dim3(4,  64), blk, 0, stream>>>(Wd3, w3t, 2048, 128);
    transpose_w_bf16<<<dim3(8,   4), blk, 0, stream>>>(Wd4, w4t, 128,  256);

    // --- encoder (fp32: argmin must match fp32 reference) ---
    sgemm_lrelu_64 <<<dim3(2, 64),  blk, 0, stream>>>(cond, We1, be1, x1,      4096, 128,  256);
    sgemm_lrelu_128<<<dim3(16, 32), blk, 0, stream>>>(x1,   We2, be2, bufA,    4096, 2048, 128);
    sgemm_lrelu_128<<<dim3(16, 32), blk, 0, stream>>>(bufA, We3, be3, bufB,    4096, 2048, 2048);
    sgemm_lrelu_128<<<dim3(16, 32), blk, 0, stream>>>(bufB, We4, be4, encoded, 4096, 2048, 2048);

    // --- VQ: idx ints into quantized-region row slots; bf16 decoder input ---
    vq_argmin<<<1024, blk, 0, stream>>>(encoded, cb, cnorm, quant);
    vq_gather_bf16<<<16384, blk, 0, stream>>>(quant, cb, qb);

    // --- decoder (bf16 MFMA, fp32 accumulate) ---
    hgemm_lrelu<1><<<dim3(16, 32), blk, 0, stream>>>(qb,  w1t, bd1, nullptr, d1b, 4096, 2048, 2048);
    hgemm_lrelu<1><<<dim3(16, 32), blk, 0, stream>>>(d1b, w2t, bd2, nullptr, d2b, 4096, 2048, 2048);
    hgemm_lrelu<1><<<dim3(1,  32), blk, 0, stream>>>(d2b, w3t, bd3, nullptr, y3b, 4096, 128,  2048);
    hgemm_lrelu<0><<<dim3(2,  32), blk, 0, stream>>>(y3b, w4t, bd4, recon, nullptr, 4096, 256, 128);

    // --- one-hot rows (wipes disc scratch; reads idx from quant region) ---
    onehot_rows<<<65536, blk, 0, stream>>>(quant, disc);
    // --- final fp32 quantized (consumes idx slots in-place) ---
    vq_gather_final<<<16384, blk, 0, stream>>>(quant, cb);
}